// Round 9
// baseline (140.394 us; speedup 1.0000x reference)
//
#include <hip/hip_runtime.h>
#include <stdint.h>

typedef _Float16 half4v __attribute__((ext_vector_type(4)));
typedef _Float16 half8v __attribute__((ext_vector_type(8)));
typedef float    f32x4  __attribute__((ext_vector_type(4)));
typedef __attribute__((address_space(3))) void       lds_void;
typedef const __attribute__((address_space(1))) void g_void;

#define NB 8
#define SXX 2048
#define DD 512
#define QBLK 64
#define TBLK 64
#define NITER 32

/* y tile: row-major fp16, padded rows 520 f16 = 1040 B (bank-rotate 4/row). */
#define RSB 1040u
#define BUFSZ (64u * RSB)          /* 66560 */
#define POFF  (2u * BUFSZ)         /* 133120: P[64 q][64 t] fp16, row 136 B */
#define PR    136u
#define SCOFF (POFF + 64u * PR)    /* 141824: per-q scale f32[64] */
#define TMOFF (SCOFF + 256u)       /* 142080: per-(quarter,q) tile-max f32[4][64] */
#define LOFF  (TMOFF + 1024u)      /* 143104: per-(quarter,q) l f32[4][64] */
#define LDS_BYTES 144128
#define YH_BYTES (8ull * 2048ull * 512ull * 2ull)   /* 16 MiB fp16 y */

__global__ __launch_bounds__(256)
void convert_y(const float* __restrict__ y, _Float16* __restrict__ yh) {
  const int i = (blockIdx.x * 256 + threadIdx.x) * 8;
  f32x4 f0 = *(const f32x4*)(y + i);
  f32x4 f1 = *(const f32x4*)(y + i + 4);
  half8v h;
  h[0]=(_Float16)f0[0]; h[1]=(_Float16)f0[1]; h[2]=(_Float16)f0[2]; h[3]=(_Float16)f0[3];
  h[4]=(_Float16)f1[0]; h[5]=(_Float16)f1[1]; h[6]=(_Float16)f1[2]; h[7]=(_Float16)f1[3];
  *(half8v*)(yh + i) = h;
}

template <bool USE_WS>
__global__ __launch_bounds__(512, 2)
void attn_fused(const float* __restrict__ x, const float* __restrict__ y,
                const _Float16* __restrict__ yh, float* __restrict__ out) {
  extern __shared__ char smem[];
  const int bid   = blockIdx.x;
  const int b     = bid & 7;      /* one batch per XCD -> yh batch L2-resident */
  const int qtile = bid >> 3;
  const int tid   = threadIdx.x;
  const int w     = tid >> 6;     /* 0..7 */
  const int lane  = tid & 63;
  const int l15   = lane & 15;
  const int g     = lane >> 4;
  const int qg    = w & 1;        /* q-group: 32 rows for QK */
  const int tq    = w >> 1;       /* t-quarter: 16 t */

  const float*    xb  = x + (size_t)b * SXX * DD;
  const float*    yb  = y + (size_t)b * SXX * DD;
  const _Float16* yhb = USE_WS ? (yh + (size_t)b * SXX * DD) : nullptr;
  float* outb = out + (size_t)b * SXX * (2 * DD);
  const int qbase = qtile * QBLK;

  /* async-stage tile 0 */
  if (USE_WS) {
#pragma unroll
    for (int i = 0; i < 8; ++i) {
      const int row = w * 8 + i;
      __builtin_amdgcn_global_load_lds((g_void*)(yhb + row * DD + lane * 8),
                                       (lds_void*)(smem + (uint32_t)row * RSB), 16, 0, 0);
    }
  }

  /* ---- out[:, :512] = x (exact fp32 copy) ---- */
  {
    const f32x4* src = (const f32x4*)(xb + (size_t)qbase * DD);
    for (int i = tid; i < QBLK * (DD / 4); i += 512) {
      f32x4 v = src[i];
      *(f32x4*)(outb + (size_t)(qbase + (i >> 7)) * (2 * DD) + (i & 127) * 4) = v;
    }
  }

  /* ---- Q fragments (fp16), B-operand of 16x16x32, 32 q per wave:
     qh-subtile qh: lane holds col q = qbase+qg*32+qh*16+l15, d = 32c+8g+j ---- */
  half8v bq0[16], bq1[16];
  {
    const float* xr0 = xb + (size_t)(qbase + qg * 32 + l15) * DD;
    const float* xr1 = xr0 + 16 * DD;
#pragma unroll
    for (int c = 0; c < 16; ++c) {
      const int d0 = c * 32 + g * 8;
      f32x4 f0 = *(const f32x4*)(xr0 + d0);
      f32x4 f1 = *(const f32x4*)(xr0 + d0 + 4);
      half8v h;
      h[0]=(_Float16)f0[0]; h[1]=(_Float16)f0[1]; h[2]=(_Float16)f0[2]; h[3]=(_Float16)f0[3];
      h[4]=(_Float16)f1[0]; h[5]=(_Float16)f1[1]; h[6]=(_Float16)f1[2]; h[7]=(_Float16)f1[3];
      bq0[c] = h;
      f0 = *(const f32x4*)(xr1 + d0);
      f1 = *(const f32x4*)(xr1 + d0 + 4);
      h[0]=(_Float16)f0[0]; h[1]=(_Float16)f0[1]; h[2]=(_Float16)f0[2]; h[3]=(_Float16)f0[3];
      h[4]=(_Float16)f1[0]; h[5]=(_Float16)f1[1]; h[6]=(_Float16)f1[2]; h[7]=(_Float16)f1[3];
      bq1[c] = h;
    }
  }

  if (!USE_WS) {
#pragma unroll
    for (int k = 0; k < 8; ++k) {
      const int u = tid + k * 512;
      const int t = u >> 6, c8 = u & 63;
      const float* p = yb + t * DD + c8 * 8;
      f32x4 f0 = *(const f32x4*)p, f1 = *(const f32x4*)(p + 4);
      half8v h;
      h[0]=(_Float16)f0[0]; h[1]=(_Float16)f0[1]; h[2]=(_Float16)f0[2]; h[3]=(_Float16)f0[3];
      h[4]=(_Float16)f1[0]; h[5]=(_Float16)f1[1]; h[6]=(_Float16)f1[2]; h[7]=(_Float16)f1[3];
      *(half8v*)(smem + (uint32_t)t * RSB + (uint32_t)c8 * 16u) = h;
    }
  }

  f32x4 acc[4][4];   /* [qq][dtl]: a[qbase+qq*16+4g+r][w*64+dtl*16+l15] */
#pragma unroll
  for (int i = 0; i < 4; ++i)
#pragma unroll
    for (int j = 0; j < 4; ++j) acc[i][j] = (f32x4){0.f, 0.f, 0.f, 0.f};
  float mrun0 = -3.0e38f, mrun1 = -3.0e38f, lrun0 = 0.0f, lrun1 = 0.0f;

  __syncthreads();

  for (int it = 0; it < NITER; ++it) {
    const uint32_t cb  = (uint32_t)(it & 1) * BUFSZ;
    const uint32_t nb2 = cb ^ BUFSZ;

    /* async-issue next tile into the other buffer */
    if (USE_WS && it + 1 < NITER) {
      const _Float16* src = yhb + (size_t)(it + 1) * TBLK * DD;
#pragma unroll
      for (int i = 0; i < 8; ++i) {
        const int row = w * 8 + i;
        __builtin_amdgcn_global_load_lds((g_void*)(src + row * DD + lane * 8),
                                         (lds_void*)(smem + nb2 + (uint32_t)row * RSB), 16, 0, 0);
      }
    }

    /* ---- QK^T swapped: wave (qg,tq) does 32q x 16t; each af read feeds 2 MFMAs.
       C: lane holds q-col = l15 (within qh-subtile), t-row = tq*16 + 4g + r. ---- */
    f32x4 st0 = (f32x4){0.f, 0.f, 0.f, 0.f};
    f32x4 st1 = (f32x4){0.f, 0.f, 0.f, 0.f};
#pragma unroll
    for (int c = 0; c < 16; ++c) {
      const half8v af = *(const half8v*)(smem + cb +
          (uint32_t)(tq * 16 + l15) * RSB + 64u * (uint32_t)c + 16u * (uint32_t)g);
      st0 = __builtin_amdgcn_mfma_f32_16x16x32_f16(af, bq0[c], st0, 0, 0, 0);
      st1 = __builtin_amdgcn_mfma_f32_16x16x32_f16(af, bq1[c], st1, 0, 0, 0);
    }

    /* ---- per-qh tile-max over this wave's 16 t; 4-way exchange ---- */
    float tmax0 = fmaxf(fmaxf(st0[0], st0[1]), fmaxf(st0[2], st0[3]));
    float tmax1 = fmaxf(fmaxf(st1[0], st1[1]), fmaxf(st1[2], st1[3]));
    tmax0 = fmaxf(tmax0, __shfl_xor(tmax0, 16));
    tmax0 = fmaxf(tmax0, __shfl_xor(tmax0, 32));
    tmax1 = fmaxf(tmax1, __shfl_xor(tmax1, 16));
    tmax1 = fmaxf(tmax1, __shfl_xor(tmax1, 32));
    if (g == 0) {
      ((float*)(smem + TMOFF))[tq * 64 + qg * 32 + l15]      = tmax0;
      ((float*)(smem + TMOFF))[tq * 64 + qg * 32 + 16 + l15] = tmax1;
    }
    __syncthreads();   /* B-mid: tile-maxes visible */
    const float* tmb = (const float*)(smem + TMOFF);
    const int qi0 = qg * 32 + l15, qi1 = qi0 + 16;
    const float mnew0 = fmaxf(mrun0,
        fmaxf(fmaxf(tmb[qi0], tmb[64 + qi0]), fmaxf(tmb[128 + qi0], tmb[192 + qi0])));
    const float mnew1 = fmaxf(mrun1,
        fmaxf(fmaxf(tmb[qi1], tmb[64 + qi1]), fmaxf(tmb[128 + qi1], tmb[192 + qi1])));

    float pv0[4], pv1[4], rs0 = 0.f, rs1 = 0.f;
#pragma unroll
    for (int r = 0; r < 4; ++r) {
      pv0[r] = __expf(st0[r] - mnew0); rs0 += pv0[r];
      pv1[r] = __expf(st1[r] - mnew1); rs1 += pv1[r];
    }
    rs0 += __shfl_xor(rs0, 16); rs0 += __shfl_xor(rs0, 32);
    rs1 += __shfl_xor(rs1, 16); rs1 += __shfl_xor(rs1, 32);
    const float scale0 = __expf(mrun0 - mnew0);
    const float scale1 = __expf(mrun1 - mnew1);
    lrun0 = lrun0 * scale0 + rs0;  mrun0 = mnew0;
    lrun1 = lrun1 * scale1 + rs1;  mrun1 = mnew1;

    /* write P[q][t = tq*16+4g+r] (fp16); scale once per q (tq==0 wave) */
    {
      half4v hv;
      hv[0]=(_Float16)pv0[0]; hv[1]=(_Float16)pv0[1]; hv[2]=(_Float16)pv0[2]; hv[3]=(_Float16)pv0[3];
      *(half4v*)(smem + POFF + (uint32_t)qi0 * PR + (uint32_t)(tq * 32 + g * 8)) = hv;
      hv[0]=(_Float16)pv1[0]; hv[1]=(_Float16)pv1[1]; hv[2]=(_Float16)pv1[2]; hv[3]=(_Float16)pv1[3];
      *(half4v*)(smem + POFF + (uint32_t)qi1 * PR + (uint32_t)(tq * 32 + g * 8)) = hv;
    }
    if (tq == 0 && g == 0) {
      ((float*)(smem + SCOFF))[qi0] = scale0;
      ((float*)(smem + SCOFF))[qi1] = scale1;
    }

    if (!USE_WS && it + 1 < NITER) {
      const float* ybt = yb + (size_t)(it + 1) * TBLK * DD;
#pragma unroll
      for (int k = 0; k < 8; ++k) {
        const int u = tid + k * 512;
        const int t = u >> 6, c8 = u & 63;
        const float* p = ybt + t * DD + c8 * 8;
        f32x4 f0 = *(const f32x4*)p, f1 = *(const f32x4*)(p + 4);
        half8v h;
        h[0]=(_Float16)f0[0]; h[1]=(_Float16)f0[1]; h[2]=(_Float16)f0[2]; h[3]=(_Float16)f0[3];
        h[4]=(_Float16)f1[0]; h[5]=(_Float16)f1[1]; h[6]=(_Float16)f1[2]; h[7]=(_Float16)f1[3];
        *(half8v*)(smem + nb2 + (uint32_t)t * RSB + (uint32_t)c8 * 16u) = h;
      }
    }

    __syncthreads();   /* B1: P/scale visible, staging drained */

    /* ---- PV: all 8 waves, disjoint 64-d slices; two ch-batches ---- */
    {
#pragma unroll
      for (int qq = 0; qq < 4; ++qq) {
        const f32x4 s4 = *(const f32x4*)(smem + SCOFF + (uint32_t)(qq * 16 + 4 * g) * 4u);
#pragma unroll
        for (int dtl = 0; dtl < 4; ++dtl) {
          acc[qq][dtl][0] *= s4[0]; acc[qq][dtl][1] *= s4[1];
          acc[qq][dtl][2] *= s4[2]; acc[qq][dtl][3] *= s4[3];
        }
      }
      __builtin_amdgcn_sched_barrier(0);

      const uint32_t pb = POFF + (uint32_t)l15 * PR + (uint32_t)g * 8u;
      const uint32_t tb = cb + (uint32_t)(4 * g + (l15 >> 2)) * RSB +
                          (uint32_t)(l15 & 3) * 8u + (uint32_t)w * 128u;
#pragma unroll
      for (int ch = 0; ch < 2; ++ch) {
        half4v palo[4], pahi[4];
#pragma unroll
        for (int qq = 0; qq < 4; ++qq) {
          const uint32_t a = pb + (uint32_t)qq * (16u * PR) + (uint32_t)ch * 64u;
          asm volatile("ds_read_b64 %0, %1" : "=v"(palo[qq]) : "v"(a));
          asm volatile("ds_read_b64 %0, %1" : "=v"(pahi[qq]) : "v"(a + 32u));
        }
        half4v blo[4], bhi[4];
#pragma unroll
        for (int dtl = 0; dtl < 4; ++dtl) {
          const uint32_t a = tb + (uint32_t)ch * (32u * RSB) + (uint32_t)dtl * 32u;
          asm volatile("ds_read_b64_tr_b16 %0, %1" : "=v"(blo[dtl]) : "v"(a));
          asm volatile("ds_read_b64_tr_b16 %0, %1" : "=v"(bhi[dtl]) : "v"(a + 16u * RSB));
        }
        asm volatile("s_waitcnt lgkmcnt(0)" ::: "memory");
        __builtin_amdgcn_sched_barrier(0);
#pragma unroll
        for (int dtl = 0; dtl < 4; ++dtl) {
          const half8v b8 = __builtin_shufflevector(blo[dtl], bhi[dtl], 0, 1, 2, 3, 4, 5, 6, 7);
#pragma unroll
          for (int qq = 0; qq < 4; ++qq) {
            const half8v pa = __builtin_shufflevector(palo[qq], pahi[qq],
                                                      0, 1, 2, 3, 4, 5, 6, 7);
            acc[qq][dtl] = __builtin_amdgcn_mfma_f32_16x16x32_f16(pa, b8, acc[qq][dtl], 0, 0, 0);
          }
        }
      }
    }
    __syncthreads();   /* B2: PV reads of P/cbuf done */
  }

  /* ---- epilogue: l = sum of 4 quarters, then store a into out[:, 512:] ---- */
  if (g == 0) {
    ((float*)(smem + LOFF))[tq * 64 + qg * 32 + l15]      = lrun0;
    ((float*)(smem + LOFF))[tq * 64 + qg * 32 + 16 + l15] = lrun1;
  }
  __syncthreads();
#pragma unroll
  for (int qq = 0; qq < 4; ++qq) {
    const f32x4 l0 = *(const f32x4*)(smem + LOFF + (uint32_t)(qq * 16 + 4 * g) * 4u);
    const f32x4 l1 = *(const f32x4*)(smem + LOFF + 256u + (uint32_t)(qq * 16 + 4 * g) * 4u);
    const f32x4 l2 = *(const f32x4*)(smem + LOFF + 512u + (uint32_t)(qq * 16 + 4 * g) * 4u);
    const f32x4 l3 = *(const f32x4*)(smem + LOFF + 768u + (uint32_t)(qq * 16 + 4 * g) * 4u);
    f32x4 iv;
#pragma unroll
    for (int r = 0; r < 4; ++r) iv[r] = 1.0f / (l0[r] + l1[r] + l2[r] + l3[r]);
#pragma unroll
    for (int dtl = 0; dtl < 4; ++dtl) {
#pragma unroll
      for (int r = 0; r < 4; ++r) {
        const int q = qbase + qq * 16 + 4 * g + r;
        outb[(size_t)q * (2 * DD) + DD + w * 64 + dtl * 16 + l15] = acc[qq][dtl][r] * iv[r];
      }
    }
  }
}

extern "C" void kernel_launch(void* const* d_in, const int* in_sizes, int n_in,
                              void* d_out, int out_size, void* d_ws, size_t ws_size,
                              hipStream_t stream) {
  (void)in_sizes; (void)n_in; (void)out_size;
  const float* x = (const float*)d_in[0];
  const float* y = (const float*)d_in[1];
  float* out = (float*)d_out;
  static_assert(LDS_BYTES <= 160 * 1024, "LDS over budget");
  const bool use_ws = (ws_size >= YH_BYTES);
  if (use_ws) {
    _Float16* yh = (_Float16*)d_ws;
    hipLaunchKernelGGL(convert_y, dim3(4096), dim3(256), 0, stream, y, yh);
    hipFuncSetAttribute((const void*)attn_fused<true>,
                        hipFuncAttributeMaxDynamicSharedMemorySize, LDS_BYTES);
    hipLaunchKernelGGL((attn_fused<true>), dim3((SXX / QBLK) * NB), dim3(512),
                       LDS_BYTES, stream, x, y, yh, out);
  } else {
    hipFuncSetAttribute((const void*)attn_fused<false>,
                        hipFuncAttributeMaxDynamicSharedMemorySize, LDS_BYTES);
    hipLaunchKernelGGL((attn_fused<false>), dim3((SXX / QBLK) * NB), dim3(512),
                       LDS_BYTES, stream, x, y, nullptr, out);
  }
}

// Round 10
// 118.884 us; speedup vs baseline: 1.1809x; 1.1809x over previous
//
#include <hip/hip_runtime.h>
#include <stdint.h>

typedef _Float16 half4v __attribute__((ext_vector_type(4)));
typedef _Float16 half8v __attribute__((ext_vector_type(8)));
typedef float    f32x4  __attribute__((ext_vector_type(4)));
typedef __attribute__((address_space(3))) void       lds_void;
typedef const __attribute__((address_space(1))) void g_void;

#define NB 8
#define SXX 2048
#define DD 512
#define QBLK 64
#define TBLK 64
#define NITER 32

/* y tile: row-major fp16, padded rows 520 f16 = 1040 B (bank-rotate 4/row). */
#define RSB 1040u
#define BUFSZ (64u * RSB)          /* 66560 */
#define POFF  (2u * BUFSZ)         /* 133120: P[64 q][64 t] fp16, row 136 B */
#define PR    136u
#define SCOFF (POFF + 64u * PR)    /* 141824: per-q scale f32[64] */
#define TMOFF (SCOFF + 256u)       /* 142080: per-(half,q) tile-max f32[2][64] */
#define LOFF  (TMOFF + 512u)       /* 142592: per-(half,q) l f32[2][64] */
#define LDS_BYTES 143104
#define YH_BYTES (8ull * 2048ull * 512ull * 2ull)   /* 16 MiB fp16 y */

__global__ __launch_bounds__(256)
void convert_y(const float* __restrict__ y, _Float16* __restrict__ yh) {
  const int i = (blockIdx.x * 256 + threadIdx.x) * 8;
  f32x4 f0 = *(const f32x4*)(y + i);
  f32x4 f1 = *(const f32x4*)(y + i + 4);
  half8v h;
  h[0]=(_Float16)f0[0]; h[1]=(_Float16)f0[1]; h[2]=(_Float16)f0[2]; h[3]=(_Float16)f0[3];
  h[4]=(_Float16)f1[0]; h[5]=(_Float16)f1[1]; h[6]=(_Float16)f1[2]; h[7]=(_Float16)f1[3];
  *(half8v*)(yh + i) = h;
}

template <bool USE_WS>
__global__ __launch_bounds__(512, 2)
void attn_fused(const float* __restrict__ x, const float* __restrict__ y,
                const _Float16* __restrict__ yh, float* __restrict__ out) {
  extern __shared__ char smem[];
  const int bid   = blockIdx.x;
  const int b     = bid & 7;      /* one batch per XCD -> yh batch L2-resident */
  const int qtile = bid >> 3;
  const int tid   = threadIdx.x;
  const int w     = tid >> 6;     /* 0..7 */
  const int lane  = tid & 63;
  const int l15   = lane & 15;
  const int g     = lane >> 4;
  const int qw    = w & 3;        /* q-subtile (16 rows) for QK */
  const int th    = w >> 2;       /* t-half (32 t) for QK */

  const float*    xb  = x + (size_t)b * SXX * DD;
  const float*    yb  = y + (size_t)b * SXX * DD;
  const _Float16* yhb = USE_WS ? (yh + (size_t)b * SXX * DD) : nullptr;
  float* outb = out + (size_t)b * SXX * (2 * DD);
  const int qbase = qtile * QBLK;

  /* async-stage tile 0 into buf0 */
  if (USE_WS) {
#pragma unroll
    for (int i = 0; i < 8; ++i) {
      const int row = w * 8 + i;
      __builtin_amdgcn_global_load_lds((g_void*)(yhb + row * DD + lane * 8),
                                       (lds_void*)(smem + (uint32_t)row * RSB), 16, 0, 0);
    }
  }

  /* ---- out[:, :512] = x (exact fp32 copy) ---- */
  {
    const f32x4* src = (const f32x4*)(xb + (size_t)qbase * DD);
    for (int i = tid; i < QBLK * (DD / 4); i += 512) {
      f32x4 v = src[i];
      *(f32x4*)(outb + (size_t)(qbase + (i >> 7)) * (2 * DD) + (i & 127) * 4) = v;
    }
  }

  /* ---- Q fragments (fp16), B-operand of 16x16x32 ---- */
  half8v bq[16];
  {
    const float* xr = xb + (size_t)(qbase + qw * 16 + l15) * DD;
#pragma unroll
    for (int c = 0; c < 16; ++c) {
      const int d0 = c * 32 + g * 8;
      f32x4 f0 = *(const f32x4*)(xr + d0);
      f32x4 f1 = *(const f32x4*)(xr + d0 + 4);
      half8v h;
      h[0] = (_Float16)f0[0]; h[1] = (_Float16)f0[1];
      h[2] = (_Float16)f0[2]; h[3] = (_Float16)f0[3];
      h[4] = (_Float16)f1[0]; h[5] = (_Float16)f1[1];
      h[6] = (_Float16)f1[2]; h[7] = (_Float16)f1[3];
      bq[c] = h;
    }
  }

  if (!USE_WS) {
#pragma unroll
    for (int k = 0; k < 8; ++k) {
      const int u = tid + k * 512;
      const int t = u >> 6, c8 = u & 63;
      const float* p = yb + t * DD + c8 * 8;
      f32x4 f0 = *(const f32x4*)p, f1 = *(const f32x4*)(p + 4);
      half8v h;
      h[0]=(_Float16)f0[0]; h[1]=(_Float16)f0[1]; h[2]=(_Float16)f0[2]; h[3]=(_Float16)f0[3];
      h[4]=(_Float16)f1[0]; h[5]=(_Float16)f1[1]; h[6]=(_Float16)f1[2]; h[7]=(_Float16)f1[3];
      *(half8v*)(smem + (uint32_t)t * RSB + (uint32_t)c8 * 16u) = h;
    }
  }

  f32x4 acc[4][4];   /* [qq][dtl]: a[qbase+qq*16+4g+r][w*64+dtl*16+l15] */
#pragma unroll
  for (int i = 0; i < 4; ++i)
#pragma unroll
    for (int j = 0; j < 4; ++j) acc[i][j] = (f32x4){0.f, 0.f, 0.f, 0.f};
  float mrun = -3.0e38f, lrun = 0.0f;
  f32x4 st[2];   /* S^T frags for the CURRENT tile, carried across phases */

  __syncthreads();   /* tile-0 staging drained */

  /* ---- QK(0) from buf0 ---- */
  st[0] = (f32x4){0.f, 0.f, 0.f, 0.f};
  st[1] = (f32x4){0.f, 0.f, 0.f, 0.f};
#pragma unroll
  for (int c = 0; c < 16; ++c) {
    const uint32_t db = 64u * (uint32_t)c + 16u * (uint32_t)g;
#pragma unroll
    for (int tt = 0; tt < 2; ++tt) {
      const half8v af =
          *(const half8v*)(smem + (uint32_t)(th * 32 + tt * 16 + l15) * RSB + db);
      st[tt] = __builtin_amdgcn_mfma_f32_16x16x32_f16(af, bq[c], st[tt], 0, 0, 0);
    }
  }
  {
    float tmax = -3.0e38f;
#pragma unroll
    for (int tt = 0; tt < 2; ++tt)
#pragma unroll
      for (int r = 0; r < 4; ++r) tmax = fmaxf(tmax, st[tt][r]);
    tmax = fmaxf(tmax, __shfl_xor(tmax, 16));
    tmax = fmaxf(tmax, __shfl_xor(tmax, 32));
    if (g == 0) ((float*)(smem + TMOFF))[th * 64 + qw * 16 + l15] = tmax;
  }
  __syncthreads();   /* B2(-1): tile-0 tmax visible */

  for (int it = 0; it < NITER; ++it) {
    const uint32_t cb  = (uint32_t)(it & 1) * BUFSZ;
    const uint32_t nb2 = cb ^ BUFSZ;

    /* ---- phase 1: stage-issue y(it+1); softmax(it); write P/scale ---- */
    if (USE_WS && it + 1 < NITER) {
      const _Float16* src = yhb + (size_t)(it + 1) * TBLK * DD;
#pragma unroll
      for (int i = 0; i < 8; ++i) {
        const int row = w * 8 + i;
        __builtin_amdgcn_global_load_lds((g_void*)(src + row * DD + lane * 8),
                                         (lds_void*)(smem + nb2 + (uint32_t)row * RSB), 16, 0, 0);
      }
    }

    {
      const float* tmb = (const float*)(smem + TMOFF);
      const float tm0 = tmb[qw * 16 + l15];
      const float tm1 = tmb[64 + qw * 16 + l15];
      const float mnew = fmaxf(mrun, fmaxf(tm0, tm1));   /* common across partners */
      float pvv[8];
      float rsum = 0.f;
#pragma unroll
      for (int tt = 0; tt < 2; ++tt)
#pragma unroll
        for (int r = 0; r < 4; ++r) {
          const float e = __expf(st[tt][r] - mnew);
          pvv[tt * 4 + r] = e;
          rsum += e;
        }
      rsum += __shfl_xor(rsum, 16);
      rsum += __shfl_xor(rsum, 32);
      const float scale = __expf(mrun - mnew);   /* identical for both partners */
      lrun = lrun * scale + rsum;
      mrun = mnew;

      /* write P[q = qw*16+l15][t = th*32+16tt+4g+r]; scale once per q */
#pragma unroll
      for (int tt = 0; tt < 2; ++tt) {
        half4v hv;
        hv[0] = (_Float16)pvv[tt * 4 + 0]; hv[1] = (_Float16)pvv[tt * 4 + 1];
        hv[2] = (_Float16)pvv[tt * 4 + 2]; hv[3] = (_Float16)pvv[tt * 4 + 3];
        *(half4v*)(smem + POFF + (uint32_t)(qw * 16 + l15) * PR +
                   (uint32_t)(th * 64 + tt * 32) + (uint32_t)g * 8u) = hv;
      }
      if (th == 0 && g == 0) ((float*)(smem + SCOFF))[qw * 16 + l15] = scale;
    }

    if (!USE_WS && it + 1 < NITER) {
      const float* ybt = yb + (size_t)(it + 1) * TBLK * DD;
#pragma unroll
      for (int k = 0; k < 8; ++k) {
        const int u = tid + k * 512;
        const int t = u >> 6, c8 = u & 63;
        const float* p = ybt + t * DD + c8 * 8;
        f32x4 f0 = *(const f32x4*)p, f1 = *(const f32x4*)(p + 4);
        half8v h;
        h[0]=(_Float16)f0[0]; h[1]=(_Float16)f0[1]; h[2]=(_Float16)f0[2]; h[3]=(_Float16)f0[3];
        h[4]=(_Float16)f1[0]; h[5]=(_Float16)f1[1]; h[6]=(_Float16)f1[2]; h[7]=(_Float16)f1[3];
        *(half8v*)(smem + nb2 + (uint32_t)t * RSB + (uint32_t)c8 * 16u) = h;
      }
    }

    __syncthreads();   /* B1: P/scale visible; y(it+1) staging drained */

    /* ---- phase 2: acc rescale; QK(it+1); PV(it) ---- */
    {
#pragma unroll
      for (int qq = 0; qq < 4; ++qq) {
        const f32x4 s4 = *(const f32x4*)(smem + SCOFF + (uint32_t)(qq * 16 + 4 * g) * 4u);
#pragma unroll
        for (int dtl = 0; dtl < 4; ++dtl) {
          acc[qq][dtl][0] *= s4[0]; acc[qq][dtl][1] *= s4[1];
          acc[qq][dtl][2] *= s4[2]; acc[qq][dtl][3] *= s4[3];
        }
      }

      /* QK(it+1) from nb2 (compiler-scheduled; before asm PV reads) */
      if (it + 1 < NITER) {
        st[0] = (f32x4){0.f, 0.f, 0.f, 0.f};
        st[1] = (f32x4){0.f, 0.f, 0.f, 0.f};
#pragma unroll
        for (int c = 0; c < 16; ++c) {
          const uint32_t db = nb2 + 64u * (uint32_t)c + 16u * (uint32_t)g;
#pragma unroll
          for (int tt = 0; tt < 2; ++tt) {
            const half8v af =
                *(const half8v*)(smem + (uint32_t)(th * 32 + tt * 16 + l15) * RSB + db);
            st[tt] = __builtin_amdgcn_mfma_f32_16x16x32_f16(af, bq[c], st[tt], 0, 0, 0);
          }
        }
        float tmax = -3.0e38f;
#pragma unroll
        for (int tt = 0; tt < 2; ++tt)
#pragma unroll
          for (int r = 0; r < 4; ++r) tmax = fmaxf(tmax, st[tt][r]);
        tmax = fmaxf(tmax, __shfl_xor(tmax, 16));
        tmax = fmaxf(tmax, __shfl_xor(tmax, 32));
        if (g == 0) ((float*)(smem + TMOFF))[th * 64 + qw * 16 + l15] = tmax;
      }

      /* PV(it): batch-issue all LDS reads, single wait, 32 MFMAs */
      __builtin_amdgcn_sched_barrier(0);
      half4v palo[4][2], pahi[4][2];
      const uint32_t pb = POFF + (uint32_t)l15 * PR + (uint32_t)g * 8u;
#pragma unroll
      for (int qq = 0; qq < 4; ++qq)
#pragma unroll
        for (int ch = 0; ch < 2; ++ch) {
          const uint32_t a = pb + (uint32_t)qq * (16u * PR) + (uint32_t)ch * 64u;
          asm volatile("ds_read_b64 %0, %1" : "=v"(palo[qq][ch]) : "v"(a));
          asm volatile("ds_read_b64 %0, %1" : "=v"(pahi[qq][ch]) : "v"(a + 32u));
        }
      half4v blo[8], bhi[8];
      const uint32_t tb = cb + (uint32_t)(4 * g + (l15 >> 2)) * RSB +
                          (uint32_t)(l15 & 3) * 8u + (uint32_t)w * 128u;
#pragma unroll
      for (int fr = 0; fr < 8; ++fr) {
        const uint32_t a = tb + (uint32_t)(fr >> 2) * (32u * RSB) + (uint32_t)(fr & 3) * 32u;
        asm volatile("ds_read_b64_tr_b16 %0, %1" : "=v"(blo[fr]) : "v"(a));
        asm volatile("ds_read_b64_tr_b16 %0, %1" : "=v"(bhi[fr]) : "v"(a + 16u * RSB));
      }
      asm volatile("s_waitcnt lgkmcnt(0)" ::: "memory");
      __builtin_amdgcn_sched_barrier(0);

#pragma unroll
      for (int fr = 0; fr < 8; ++fr) {
        const half8v b8 = __builtin_shufflevector(blo[fr], bhi[fr], 0, 1, 2, 3, 4, 5, 6, 7);
        const int ch = fr >> 2, dtl = fr & 3;
#pragma unroll
        for (int qq = 0; qq < 4; ++qq) {
          const half8v pa = __builtin_shufflevector(palo[qq][ch], pahi[qq][ch],
                                                    0, 1, 2, 3, 4, 5, 6, 7);
          acc[qq][dtl] = __builtin_amdgcn_mfma_f32_16x16x32_f16(pa, b8, acc[qq][dtl], 0, 0, 0);
        }
      }
    }
    __syncthreads();   /* B2: tmax(it+1) visible; P/cbuf reads done */
  }

  /* ---- epilogue: l = l(th=0) + l(th=1), then store a into out[:, 512:] ---- */
  if (g == 0) ((float*)(smem + LOFF))[th * 64 + qw * 16 + l15] = lrun;
  __syncthreads();
#pragma unroll
  for (int qq = 0; qq < 4; ++qq) {
    const f32x4 l0 = *(const f32x4*)(smem + LOFF + (uint32_t)(qq * 16 + 4 * g) * 4u);
    const f32x4 l1 = *(const f32x4*)(smem + LOFF + 256u + (uint32_t)(qq * 16 + 4 * g) * 4u);
    f32x4 iv;
#pragma unroll
    for (int r = 0; r < 4; ++r) iv[r] = 1.0f / (l0[r] + l1[r]);
#pragma unroll
    for (int dtl = 0; dtl < 4; ++dtl) {
#pragma unroll
      for (int r = 0; r < 4; ++r) {
        const int q = qbase + qq * 16 + 4 * g + r;
        outb[(size_t)q * (2 * DD) + DD + w * 64 + dtl * 16 + l15] = acc[qq][dtl][r] * iv[r];
      }
    }
  }
}

extern "C" void kernel_launch(void* const* d_in, const int* in_sizes, int n_in,
                              void* d_out, int out_size, void* d_ws, size_t ws_size,
                              hipStream_t stream) {
  (void)in_sizes; (void)n_in; (void)out_size;
  const float* x = (const float*)d_in[0];
  const float* y = (const float*)d_in[1];
  float* out = (float*)d_out;
  static_assert(LDS_BYTES <= 160 * 1024, "LDS over budget");
  const bool use_ws = (ws_size >= YH_BYTES);
  if (use_ws) {
    _Float16* yh = (_Float16*)d_ws;
    hipLaunchKernelGGL(convert_y, dim3(4096), dim3(256), 0, stream, y, yh);
    hipFuncSetAttribute((const void*)attn_fused<true>,
                        hipFuncAttributeMaxDynamicSharedMemorySize, LDS_BYTES);
    hipLaunchKernelGGL((attn_fused<true>), dim3((SXX / QBLK) * NB), dim3(512),
                       LDS_BYTES, stream, x, y, yh, out);
  } else {
    hipFuncSetAttribute((const void*)attn_fused<false>,
                        hipFuncAttributeMaxDynamicSharedMemorySize, LDS_BYTES);
    hipLaunchKernelGGL((attn_fused<false>), dim3((SXX / QBLK) * NB), dim3(512),
                       LDS_BYTES, stream, x, y, nullptr, out);
  }
}